// Round 4
// baseline (1415.117 us; speedup 1.0000x reference)
//
#include <hip/hip_runtime.h>
#include <hip/hip_bf16.h>
#include <cstdint>
#include <cstddef>

typedef __attribute__((ext_vector_type(8))) short bf16x8;
typedef __attribute__((ext_vector_type(4))) float f32x4;
typedef __attribute__((ext_vector_type(4))) unsigned int u32x4;
typedef __attribute__((ext_vector_type(2))) unsigned int u32x2;

// round-to-nearest-even f32 -> bf16 bits
__device__ __forceinline__ unsigned short f2bf(float f) {
  unsigned u = __float_as_uint(f);
  return (unsigned short)((u + 0x7fffu + ((u >> 16) & 1u)) >> 16);
}

// ---------------- transpose + cast: W[1024][4096] f32 -> WT[4096][1024] bf16
__global__ __launch_bounds__(256) void transpose_cast_k(const float* __restrict__ W,
                                                        unsigned short* __restrict__ WT) {
  __shared__ float tile[32][33];
  const int bn = blockIdx.x * 32, bk = blockIdx.y * 32;
  const int tx = threadIdx.x & 31, ty = threadIdx.x >> 5;  // ty 0..7
#pragma unroll
  for (int i = 0; i < 4; ++i) {
    const int k = ty + i * 8;
    tile[k][tx] = W[(size_t)(bk + k) * 4096 + bn + tx];
  }
  __syncthreads();
#pragma unroll
  for (int i = 0; i < 4; ++i) {
    const int n = ty + i * 8;
    WT[(size_t)(bn + n) * 1024 + bk + tx] = f2bf(tile[tx][n]);
  }
}

// ---------------- embedding gather -> bf16 [8192][1024]
__global__ __launch_bounds__(256) void embed_gather_k(const int* __restrict__ ids,
                                                      const float* __restrict__ emb,
                                                      unsigned short* __restrict__ x) {
  const int bt = blockIdx.x;
  const int id = ids[bt];
  const float4 v = ((const float4*)(emb + (size_t)id * 1024))[threadIdx.x];
  union { unsigned short u[4]; unsigned long long ll; } o;
  o.u[0] = f2bf(v.x); o.u[1] = f2bf(v.y); o.u[2] = f2bf(v.z); o.u[3] = f2bf(v.w);
  *(unsigned long long*)(x + (size_t)bt * 1024 + threadIdx.x * 4) = o.ll;
}

// ---------------- GEMM: C[M=8192][4096] f32 = A[M][1024] bf16 @ BT[4096][1024]^T + bias
__global__ __launch_bounds__(256) void gemm_bt_k(const unsigned short* __restrict__ A,
                                                 const unsigned short* __restrict__ BT,
                                                 const float* __restrict__ bias,
                                                 float* __restrict__ C) {
  __shared__ char sA[128 * 128];  // 128 rows x 64 bf16 (128B rows), XOR-swizzled
  __shared__ char sB[128 * 128];
  const int bid = blockIdx.x;
  const int bm = (bid >> 5) * 128;
  const int bn = (bid & 31) * 128;
  const int tid = threadIdx.x, lane = tid & 63;
  const int wv = tid >> 6, wm = wv >> 1, wn = wv & 1;
  const int lrow = lane & 15, lk = (lane >> 4) * 16;  // frag k byte offset
  f32x4 acc[4][4] = {};
  for (int kt = 0; kt < 16; ++kt) {
    const int k0 = kt * 64;
    bf16x8 av[4], bv[4];
#pragma unroll
    for (int i = 0; i < 4; ++i) {
      const int ch = i * 256 + tid;         // 0..1023
      const int row = ch >> 3, c = ch & 7;  // 16B chunk within row
      av[i] = *(const bf16x8*)(A + (size_t)(bm + row) * 1024 + k0 + c * 8);
      bv[i] = *(const bf16x8*)(BT + (size_t)(bn + row) * 1024 + k0 + c * 8);
    }
    __syncthreads();  // prior iter's LDS reads done
#pragma unroll
    for (int i = 0; i < 4; ++i) {
      const int ch = i * 256 + tid;
      const int row = ch >> 3, c = ch & 7;
      const int off = row * 128 + ((c * 16) ^ ((row & 7) << 4));
      *(bf16x8*)(sA + off) = av[i];
      *(bf16x8*)(sB + off) = bv[i];
    }
    __syncthreads();
#pragma unroll
    for (int kk = 0; kk < 2; ++kk) {
      bf16x8 af[4], bf_[4];
#pragma unroll
      for (int mi = 0; mi < 4; ++mi) {
        const int row = wm * 64 + mi * 16 + lrow;
        af[mi] = *(const bf16x8*)(sA + row * 128 + ((kk * 64 + lk) ^ ((row & 7) << 4)));
      }
#pragma unroll
      for (int ni = 0; ni < 4; ++ni) {
        const int row = wn * 64 + ni * 16 + lrow;
        bf_[ni] = *(const bf16x8*)(sB + row * 128 + ((kk * 64 + lk) ^ ((row & 7) << 4)));
      }
#pragma unroll
      for (int mi = 0; mi < 4; ++mi)
#pragma unroll
        for (int ni = 0; ni < 4; ++ni)
          acc[mi][ni] = __builtin_amdgcn_mfma_f32_16x16x32_bf16(af[mi], bf_[ni], acc[mi][ni], 0, 0, 0);
    }
  }
  const int cr0 = (lane >> 4) * 4;
#pragma unroll
  for (int mi = 0; mi < 4; ++mi)
#pragma unroll
    for (int ni = 0; ni < 4; ++ni) {
      const int col = bn + wn * 64 + ni * 16 + lrow;
      const float bb = bias[col];
#pragma unroll
      for (int r = 0; r < 4; ++r) {
        const int row = bm + wm * 64 + mi * 16 + cr0 + r;
        C[(size_t)row * 4096 + col] = acc[mi][ni][r] + bb;
      }
    }
}

// ---------------- persistent LSTM layer (cooperative, 256 WGs x 256 thr)
// Sync via epoch-embedded 16B packets: {4x bf16 h, u32 epoch, pad}, stored with a
// single dwordx4 sc0/sc1 (atomic at LLC). No flags, no drains. Double-buffered by
// t-parity; per-layer epoch base kills cross-layer ABA. Consumers retry stale
// packets, unpack into an XOR-swizzled LDS h-tile; zp partials alias the tile.
template <int LAYER>
__global__ __launch_bounds__(256) void lstm_layer_k(
    const float* __restrict__ xp,            // [B*T][4096], row = b*128+t
    const unsigned short* __restrict__ WhT,  // [4096][1024] bf16
    const int* __restrict__ ids,             // [64][128]
    u32x4* __restrict__ pktbuf,              // [2][64][256] 16B packets
    unsigned short* __restrict__ seqbf,      // layer0 out: [64][128][1024] bf16
    float* __restrict__ seqf,                // layer1 out: d_out seq f32
    float* __restrict__ hfin, float* __restrict__ cfin) {
  extern __shared__ __align__(16) char dlds[];  // 131072 weights + 32768 htile
  char* wlds = dlds;
  char* htile = dlds + 131072;        // [16 rows][2048B], XOR-swizzled
  float* zp = (float*)htile;          // [16][16][20] f32 partials (aliases htile)
  const int tid = threadIdx.x, lane = tid & 63, wave = tid >> 6;
  const int wg = blockIdx.x;
  const int g = wg & 3, w = wg >> 2;  // batch group, unit-block
  const int b0 = g * 16, u0 = w * 16;
  constexpr unsigned EB = LAYER * 512u;  // epoch base (never collides w/ 0xAAAAAAAA)

  // stage this WG's 64 Wh^T rows into LDS, XOR-swizzled
  for (int i = 0; i < 32; ++i) {
    const int ch = i * 256 + tid;  // 16B chunks
    const int n = ch >> 7, c = ch & 127;
    const int grow = (n >> 4) * 1024 + u0 + (n & 15);
    bf16x8 v = *(const bf16x8*)(WhT + (size_t)grow * 1024 + c * 8);
    *(bf16x8*)(wlds + n * 2048 + ((c * 16) ^ ((n & 7) << 4))) = v;
  }

  // wave0 owns gates/state: lane -> (row = lane>>2, 4 units at u0+4*(lane&3))
  const int prow = lane >> 2, pk4 = lane & 3;
  const int brow = b0 + prow;
  const int myunit = u0 + pk4 * 4;
  float cc[4] = {0.f, 0.f, 0.f, 0.f}, hh[4] = {0.f, 0.f, 0.f, 0.f};

  // init: version-0 packets (h=0, epoch EB+1) into buffer 0 — self-synchronizing
  if (wave == 0) {
    u32x4 z; z[0] = 0u; z[1] = 0u; z[2] = EB + 1u; z[3] = 0u;
    u32x4* p = pktbuf + (size_t)brow * 256 + (u0 >> 2) + pk4;
    asm volatile("global_store_dwordx4 %0, %1, off sc0 sc1" :: "v"(p), "v"(z) : "memory");
  }
  __syncthreads();  // weights staged

  // consumer coords: thread unpacks 16 packets of local row (tid>>4), pk = (tid&15)+16i
  const int crow = tid >> 4;
  const int cpk0 = tid & 15;
  const int lr = lane & 15, lkb = (lane >> 4) * 16, wq = wave * 512;
  const int asw = (lr & 7) << 4;

  for (int t = 0; t < 128; ++t) {
    __syncthreads();  // S0: prev zp reads done -> htile writable
    // ---- wave0: prefetch xp + mask (hides HBM latency under packet poll)
    f32x4 xq0 = {}, xq1 = {}, xq2 = {}, xq3 = {};
    int idv = 0;
    if (wave == 0) {
      const float* xr = xp + ((size_t)brow * 128 + t) * 4096 + myunit;
      xq0 = *(const f32x4*)(xr);
      xq1 = *(const f32x4*)(xr + 1024);
      xq2 = *(const f32x4*)(xr + 2048);
      xq3 = *(const f32x4*)(xr + 3072);
      idv = ids[brow * 128 + t];
    }
    // ---- packet volley + retry (the poll IS the data load)
    const unsigned target = EB + (unsigned)t + 1u;
    const char* pb = (const char*)pktbuf + (size_t)(t & 1) * 262144 +
                     ((size_t)(b0 + crow) * 256 + cpk0) * 16;
    u32x4 pkt[16];
#pragma unroll
    for (int i = 0; i < 16; ++i)
      asm volatile("global_load_dwordx4 %0, %1, off sc0 sc1"
                   : "=&v"(pkt[i]) : "v"(pb + i * 256) : "memory");
    asm volatile("s_waitcnt vmcnt(0)" ::: "memory");
    for (;;) {
      bool again = false;
#pragma unroll
      for (int i = 0; i < 16; ++i)
        if (pkt[i][2] != target) {
          asm volatile("global_load_dwordx4 %0, %1, off sc0 sc1"
                       : "=&v"(pkt[i]) : "v"(pb + i * 256) : "memory");
          again = true;
        }
      if (!again) break;
      asm volatile("s_waitcnt vmcnt(0)" ::: "memory");
    }
    __builtin_amdgcn_sched_barrier(0);
    // ---- unpack 4 h per packet into swizzled htile
#pragma unroll
    for (int i = 0; i < 16; ++i) {
      const int pk = cpk0 + 16 * i;
      u32x2 v; v[0] = pkt[i][0]; v[1] = pkt[i][1];
      *(u32x2*)(htile + crow * 2048 + ((pk * 8) ^ ((crow & 7) << 4))) = v;
    }
    __syncthreads();  // S1: htile ready
    // ---- A-frags from htile, B-frags from wlds, 32 MFMA per wave (k-quarter)
    bf16x8 af[8];
#pragma unroll
    for (int c = 0; c < 8; ++c)
      af[c] = *(const bf16x8*)(htile + lr * 2048 + ((wq + c * 64 + lkb) ^ asw));
    f32x4 acc[4] = {};
#pragma unroll
    for (int gg = 0; gg < 4; ++gg) {
      const int n = gg * 16 + lr;
      const char* bb = wlds + n * 2048;
      const int bx = (n & 7) << 4;
#pragma unroll
      for (int c = 0; c < 8; ++c) {
        bf16x8 bfv = *(const bf16x8*)(bb + ((wq + c * 64 + lkb) ^ bx));
        acc[gg] = __builtin_amdgcn_mfma_f32_16x16x32_bf16(af[c], bfv, acc[gg], 0, 0, 0);
      }
    }
    __syncthreads();  // S2: htile reads done -> zp region writable
    const int zr0 = (lane >> 4) * 4;
#pragma unroll
    for (int gg = 0; gg < 4; ++gg)
#pragma unroll
      for (int r = 0; r < 4; ++r)
        zp[((wave * 4 + gg) * 16 + zr0 + r) * 20 + lr] = acc[gg][r];
    __syncthreads();  // S3: partials visible
    // ---- wave0: reduce + gates + state + pack/store
    if (wave == 0) {
      f32x4 zs0 = xq0, zs1 = xq1, zs2 = xq2, zs3 = xq3;
#pragma unroll
      for (int ww = 0; ww < 4; ++ww) {
        zs0 += *(const f32x4*)(zp + ((ww * 4 + 0) * 16 + prow) * 20 + pk4 * 4);
        zs1 += *(const f32x4*)(zp + ((ww * 4 + 1) * 16 + prow) * 20 + pk4 * 4);
        zs2 += *(const f32x4*)(zp + ((ww * 4 + 2) * 16 + prow) * 20 + pk4 * 4);
        zs3 += *(const f32x4*)(zp + ((ww * 4 + 3) * 16 + prow) * 20 + pk4 * 4);
      }
#pragma unroll
      for (int u = 0; u < 4; ++u) {
        const float ig = 1.f / (1.f + __expf(-zs0[u]));
        const float fg = 1.f / (1.f + __expf(-zs1[u]));
        const float gt = 1.f - 2.f / (1.f + __expf(2.f * zs2[u]));
        const float og = 1.f / (1.f + __expf(-zs3[u]));
        const float cn = fg * cc[u] + ig * gt;
        const float hn = og * (1.f - 2.f / (1.f + __expf(2.f * cn)));
        if (idv != 0) { cc[u] = cn; hh[u] = hn; }
      }
      const unsigned p01 = (unsigned)f2bf(hh[0]) | ((unsigned)f2bf(hh[1]) << 16);
      const unsigned p23 = (unsigned)f2bf(hh[2]) | ((unsigned)f2bf(hh[3]) << 16);
      u32x4 op; op[0] = p01; op[1] = p23; op[2] = EB + (unsigned)t + 2u; op[3] = 0u;
      u32x4* dst = pktbuf + (size_t)((t + 1) & 1) * 16384 + (size_t)brow * 256 +
                   (u0 >> 2) + pk4;
      asm volatile("global_store_dwordx4 %0, %1, off sc0 sc1" :: "v"(dst), "v"(op) : "memory");
      if (LAYER == 0) {
        u32x2 sv; sv[0] = p01; sv[1] = p23;
        *(u32x2*)(seqbf + ((size_t)brow * 128 + t) * 1024 + myunit) = sv;
      } else {
        f32x4 sv; sv[0] = hh[0]; sv[1] = hh[1]; sv[2] = hh[2]; sv[3] = hh[3];
        *(f32x4*)(seqf + ((size_t)brow * 128 + t) * 1024 + myunit) = sv;
      }
    }
  }
  if (wave == 0) {
    f32x4 hv, cv;
#pragma unroll
    for (int u = 0; u < 4; ++u) { hv[u] = hh[u]; cv[u] = cc[u]; }
    *(f32x4*)(hfin + (size_t)brow * 1024 + myunit) = hv;
    *(f32x4*)(cfin + (size_t)brow * 1024 + myunit) = cv;
  }
}

extern "C" void kernel_launch(void* const* d_in, const int* in_sizes, int n_in,
                              void* d_out, int out_size, void* d_ws, size_t ws_size,
                              hipStream_t stream) {
  (void)in_sizes; (void)n_in; (void)out_size; (void)ws_size;
  const int* ids = (const int*)d_in[0];
  const float* emb = (const float*)d_in[1];
  const float* Wx0 = (const float*)d_in[2];
  const float* Wh0 = (const float*)d_in[3];
  const float* b0 = (const float*)d_in[4];
  const float* Wx1 = (const float*)d_in[5];
  const float* Wh1 = (const float*)d_in[6];
  const float* b1 = (const float*)d_in[7];
  float* out = (float*)d_out;

  char* ws = (char*)d_ws;
  const size_t SZ_WT = (size_t)4096 * 1024 * 2;  // 8 MiB
  unsigned short* WxT0 = (unsigned short*)(ws);
  unsigned short* WhT0 = (unsigned short*)(ws + SZ_WT);
  unsigned short* WxT1 = (unsigned short*)(ws + 2 * SZ_WT);
  unsigned short* WhT1 = (unsigned short*)(ws + 3 * SZ_WT);
  unsigned short* xbf = (unsigned short*)(ws + 4 * SZ_WT);                  // 16 MiB
  unsigned short* seq0 = (unsigned short*)(ws + 4 * SZ_WT + 16777216);      // 16 MiB
  u32x4* pktbuf = (u32x4*)(ws + 4 * SZ_WT + 2 * 16777216);                  // 512 KiB
  float* xpb = (float*)(ws + 4 * SZ_WT + 2 * 16777216 + 524288);            // 128 MiB

  float* h0f = out + 8388608;
  float* c0f = h0f + 65536;
  float* h1f = c0f + 65536;
  float* c1f = h1f + 65536;

  transpose_cast_k<<<dim3(128, 32), dim3(256), 0, stream>>>(Wx0, WxT0);
  transpose_cast_k<<<dim3(128, 32), dim3(256), 0, stream>>>(Wh0, WhT0);
  transpose_cast_k<<<dim3(128, 32), dim3(256), 0, stream>>>(Wx1, WxT1);
  transpose_cast_k<<<dim3(128, 32), dim3(256), 0, stream>>>(Wh1, WhT1);
  embed_gather_k<<<dim3(8192), dim3(256), 0, stream>>>(ids, emb, xbf);
  gemm_bt_k<<<dim3(2048), dim3(256), 0, stream>>>(xbf, WxT0, b0, xpb);

  hipFuncSetAttribute(reinterpret_cast<const void*>(&lstm_layer_k<0>),
                      hipFuncAttributeMaxDynamicSharedMemorySize, 163840);
  hipFuncSetAttribute(reinterpret_cast<const void*>(&lstm_layer_k<1>),
                      hipFuncAttributeMaxDynamicSharedMemorySize, 163840);

  {
    const float* xp_p = xpb;
    const unsigned short* wht = WhT0;
    const int* ids_p = ids;
    u32x4* pb_p = pktbuf;
    unsigned short* sb_p = seq0;
    float* sf_p = nullptr;
    float* hf_p = h0f;
    float* cf_p = c0f;
    void* ka[8] = {&xp_p, &wht, &ids_p, &pb_p, &sb_p, &sf_p, &hf_p, &cf_p};
    hipLaunchCooperativeKernel(reinterpret_cast<const void*>(&lstm_layer_k<0>),
                               dim3(256), dim3(256), ka, 163840u, stream);
  }
  gemm_bt_k<<<dim3(2048), dim3(256), 0, stream>>>(seq0, WxT1, b1, xpb);
  {
    const float* xp_p = xpb;
    const unsigned short* wht = WhT1;
    const int* ids_p = ids;
    u32x4* pb_p = pktbuf;
    unsigned short* sb_p = nullptr;
    float* sf_p = out;
    float* hf_p = h1f;
    float* cf_p = c1f;
    void* ka[8] = {&xp_p, &wht, &ids_p, &pb_p, &sb_p, &sf_p, &hf_p, &cf_p};
    hipLaunchCooperativeKernel(reinterpret_cast<const void*>(&lstm_layer_k<1>),
                               dim3(256), dim3(256), ka, 163840u, stream);
  }
}